// Round 2
// baseline (954.065 us; speedup 1.0000x reference)
//
#include <hip/hip_runtime.h>
#include <math.h>

#define NN 768
#define CSD 384
#define HD 12
#define CD 16
#define PQD 4
#define PVD 8
#define CZD 128
#define CATD 2112

// ws float offsets
#define OFF_Q      0u
#define OFF_K      147456u
#define OFF_V      294912u
#define OFF_QP     442368u
#define OFF_KP     552960u
#define OFF_VP     663552u
#define OFF_RAW    884736u
#define OFF_B      1327104u
#define OFF_A      8404992u
#define OFF_CAT    15482880u

__device__ __forceinline__ float wcol_val(const float* Wq, const float* Wkv,
                                          const float* Wqp, const float* Wkvp,
                                          int k, int col) {
  if (col < 192) return Wq[k*192 + col];
  if (col < 576) return Wkv[k*384 + (col-192)];
  if (col < 720) return Wqp[k*144 + (col-576)];
  return Wkvp[k*432 + (col-720)];
}
__device__ __forceinline__ float bias_val(const float* bq, const float* bkv,
                                          const float* bqp, const float* bkvp, int col) {
  if (col < 192) return bq[col];
  if (col < 576) return bkv[col-192];
  if (col < 720) return bqp[col-576];
  return bkvp[col-720];
}

// ---------------- K1: s @ [W_q | W_kv | W_qp | W_kvp] + bias ----------------
__global__ __launch_bounds__(256) void k_proj(const float* __restrict__ s,
    const float* __restrict__ Wq, const float* __restrict__ bq,
    const float* __restrict__ Wkv, const float* __restrict__ bkv,
    const float* __restrict__ Wqp, const float* __restrict__ bqp,
    const float* __restrict__ Wkvp, const float* __restrict__ bkvp,
    float* __restrict__ ws) {
  __shared__ float At[64*17];   // [m][k], padded
  __shared__ float Bt[16*64];   // [k][c]
  int t = threadIdx.x;
  int c0 = blockIdx.x * 64;
  int r0 = blockIdx.y * 64;
  float acc[4][4] = {};
  int cc = t & 15, rr = t >> 4;
  for (int kt = 0; kt < CSD; kt += 16) {
    int ka = t & 15, mb = t >> 4;
#pragma unroll
    for (int p = 0; p < 4; ++p) {
      int m = mb + p*16;
      At[m*17 + ka] = s[(r0+m)*CSD + kt + ka];
    }
    int cb = t & 63, kb = t >> 6;
#pragma unroll
    for (int p = 0; p < 4; ++p) {
      int kk = kb + p*4;
      Bt[kk*64 + cb] = wcol_val(Wq,Wkv,Wqp,Wkvp, kt+kk, c0+cb);
    }
    __syncthreads();
#pragma unroll
    for (int k = 0; k < 16; ++k) {
      float a0 = At[(rr*4+0)*17 + k];
      float a1 = At[(rr*4+1)*17 + k];
      float a2 = At[(rr*4+2)*17 + k];
      float a3 = At[(rr*4+3)*17 + k];
      float4 b4 = *(const float4*)&Bt[k*64 + cc*4];
      acc[0][0] = fmaf(a0,b4.x,acc[0][0]); acc[0][1] = fmaf(a0,b4.y,acc[0][1]);
      acc[0][2] = fmaf(a0,b4.z,acc[0][2]); acc[0][3] = fmaf(a0,b4.w,acc[0][3]);
      acc[1][0] = fmaf(a1,b4.x,acc[1][0]); acc[1][1] = fmaf(a1,b4.y,acc[1][1]);
      acc[1][2] = fmaf(a1,b4.z,acc[1][2]); acc[1][3] = fmaf(a1,b4.w,acc[1][3]);
      acc[2][0] = fmaf(a2,b4.x,acc[2][0]); acc[2][1] = fmaf(a2,b4.y,acc[2][1]);
      acc[2][2] = fmaf(a2,b4.z,acc[2][2]); acc[2][3] = fmaf(a2,b4.w,acc[2][3]);
      acc[3][0] = fmaf(a3,b4.x,acc[3][0]); acc[3][1] = fmaf(a3,b4.y,acc[3][1]);
      acc[3][2] = fmaf(a3,b4.z,acc[3][2]); acc[3][3] = fmaf(a3,b4.w,acc[3][3]);
    }
    __syncthreads();
  }
  float* qbuf = ws + OFF_Q; float* kbuf = ws + OFF_K; float* vbuf = ws + OFF_V;
  float* raw  = ws + OFF_RAW;
#pragma unroll
  for (int jj = 0; jj < 4; ++jj) {
    int col = c0 + cc*4 + jj;
    float bv = bias_val(bq,bkv,bqp,bkvp,col);
#pragma unroll
    for (int ii = 0; ii < 4; ++ii) {
      int row = r0 + rr*4 + ii;
      float val = acc[ii][jj] + bv;
      if (col < 192) {
        int h = col >> 4, c = col & 15;
        qbuf[(h*NN + row)*CD + c] = val;
      } else if (col < 576) {
        int u = col - 192; int h = u >> 5; int c2 = u & 31;
        if (c2 < 16) kbuf[(h*NN+row)*CD + c2] = val;
        else         vbuf[(h*NN+row)*CD + (c2-16)] = val;
      } else {
        raw[row*576 + (col-576)] = val;
      }
    }
  }
}

// ---------------- K1b: rotate+translate points ----------------
__global__ __launch_bounds__(256) void k_points(const float* __restrict__ rot,
    const float* __restrict__ trans, float* __restrict__ ws) {
  int tg = blockIdx.x*256 + threadIdx.x;      // < 768*192
  int n = tg / 192, pidx = tg % 192;
  const float* raw = ws + OFF_RAW + n*576;
  float v0, v1, v2;
  if (pidx < 48) { v0 = raw[pidx]; v1 = raw[48+pidx]; v2 = raw[96+pidx]; }
  else { int pp = pidx-48; v0 = raw[144+pp]; v1 = raw[288+pp]; v2 = raw[432+pp]; }
  const float* R = rot + n*9; const float* T = trans + n*3;
  float g0 = R[0]*v0 + R[1]*v1 + R[2]*v2 + T[0];
  float g1 = R[3]*v0 + R[4]*v1 + R[5]*v2 + T[1];
  float g2 = R[6]*v0 + R[7]*v1 + R[8]*v2 + T[2];
  if (pidx < 48) {
    int h = pidx >> 2, p = pidx & 3;
    float* qp = ws + OFF_QP + ((h*NN + n)*PQD + p)*3;
    qp[0]=g0; qp[1]=g1; qp[2]=g2;
  } else {
    int pp = pidx - 48; int h = pp/12; int q12 = pp - 12*h;
    if (q12 < 4) { float* kp = ws + OFF_KP + ((h*NN+n)*PQD + q12)*3; kp[0]=g0; kp[1]=g1; kp[2]=g2; }
    else         { float* vp = ws + OFF_VP + ((h*NN+n)*PVD + (q12-4))*3; vp[0]=g0; vp[1]=g1; vp[2]=g2; }
  }
}

// ---------------- K2 v3: bmat = sqrt(1/3)*(z @ W_b + b_b), layout (i,h,j) ----------------
// grid (768, 4); block 256 = 4 waves. Wave handles 16 j per pass, 3 passes (64 j/wave-set).
// Lane: jloc = (lane>>2), q = lane&3; lane covers c-float4s {q, q+4, ..., q+28}.
// 2-level shfl_xor reduce over q; all 4 q-lanes write 3 heads each.
__global__ __launch_bounds__(256) void k_bias(const float* __restrict__ z,
    const float* __restrict__ Wb, const float* __restrict__ bb, float* __restrict__ ws) {
  __shared__ float wb_sm[CZD*13];   // padded stride 13 to spread broadcast banks
  int t = threadIdx.x;
  int i  = blockIdx.x;
  int jq = blockIdx.y;
  // stage Wb
  for (int idx = t; idx < CZD*HD; idx += 256) {
    int c = idx / 12, h = idx - 12*c;
    wb_sm[c*13 + h] = Wb[idx];
  }
  __syncthreads();
  int w = t >> 6, lane = t & 63;
  int jloc = lane >> 2, q = lane & 3;
  float* bmat = ws + OFF_B;
  const float s2 = 0.57735026918962576f;
#pragma unroll
  for (int p = 0; p < 3; ++p) {
    int j = jq*192 + p*64 + w*16 + jloc;
    const float* zrow = z + ((size_t)i*NN + j)*CZD;
    float acc[12];
#pragma unroll
    for (int h = 0; h < 12; ++h) acc[h] = 0.f;
#pragma unroll
    for (int k = 0; k < 8; ++k) {
      int c4 = q + 4*k;                 // float4 index in row
      float4 z4 = *(const float4*)(zrow + 4*c4);
      const float* wbp = wb_sm + (4*c4)*13;
#pragma unroll
      for (int cc = 0; cc < 4; ++cc) {
        float zv = (cc==0) ? z4.x : (cc==1) ? z4.y : (cc==2) ? z4.z : z4.w;
        const float* wr = wbp + cc*13;
        float4 w0 = make_float4(wr[0], wr[1], wr[2], wr[3]);
        float4 w1 = make_float4(wr[4], wr[5], wr[6], wr[7]);
        float4 w2 = make_float4(wr[8], wr[9], wr[10], wr[11]);
        acc[0] = fmaf(zv, w0.x, acc[0]); acc[1] = fmaf(zv, w0.y, acc[1]);
        acc[2] = fmaf(zv, w0.z, acc[2]); acc[3] = fmaf(zv, w0.w, acc[3]);
        acc[4] = fmaf(zv, w1.x, acc[4]); acc[5] = fmaf(zv, w1.y, acc[5]);
        acc[6] = fmaf(zv, w1.z, acc[6]); acc[7] = fmaf(zv, w1.w, acc[7]);
        acc[8] = fmaf(zv, w2.x, acc[8]); acc[9] = fmaf(zv, w2.y, acc[9]);
        acc[10] = fmaf(zv, w2.z, acc[10]); acc[11] = fmaf(zv, w2.w, acc[11]);
      }
    }
    // reduce over q (4 c-slices) — butterfly so all lanes get the sum
#pragma unroll
    for (int h = 0; h < 12; ++h) {
      acc[h] += __shfl_xor(acc[h], 1);
      acc[h] += __shfl_xor(acc[h], 2);
    }
    // each q-lane writes 3 heads
#pragma unroll
    for (int r = 0; r < 3; ++r) {
      int h = q*3 + r;
      bmat[((size_t)i*HD + h)*NN + j] = s2*(acc[h] + bb[h]);
    }
  }
}

// ---------------- K3: logits + softmax -> a (h,i,j) ----------------
__global__ __launch_bounds__(256) void k_attn(
    const float* __restrict__ mask, const float* __restrict__ ss,
    const float* __restrict__ hwts, float* __restrict__ ws) {
  int h = blockIdx.x, i = blockIdx.y;
  int t = threadIdx.x;
  __shared__ float qsm[16];
  __shared__ float qpsm[12];
  __shared__ float wred[8];
  const float* qbuf = ws + OFF_Q; const float* kbuf = ws + OFF_K;
  const float* qp   = ws + OFF_QP; const float* kp  = ws + OFF_KP;
  const float* bmat = ws + OFF_B;
  float* abuf = ws + OFF_A;
  if (t < 16) qsm[t] = qbuf[(h*NN+i)*CD + t];
  else if (t < 28) qpsm[t-16] = qp[(h*NN+i)*12 + (t-16)];
  __syncthreads();
  float coef = -0.5f * 0.13608276348795434f * log1pf(__expf(hwts[h]));
  float mi = mask[i];
  const float s1 = 0.14433756729740643f;
  float l3[3], ss3[3];
#pragma unroll
  for (int jj = 0; jj < 3; ++jj) {
    int j = t + jj*256;
    const float4* kb = (const float4*)(kbuf + (h*NN+j)*CD);
    float dot = 0.f;
#pragma unroll
    for (int u = 0; u < 4; ++u) {
      float4 kv = kb[u];
      dot = fmaf(qsm[u*4+0], kv.x, dot);
      dot = fmaf(qsm[u*4+1], kv.y, dot);
      dot = fmaf(qsm[u*4+2], kv.z, dot);
      dot = fmaf(qsm[u*4+3], kv.w, dot);
    }
    const float4* kpb = (const float4*)(kp + (h*NN+j)*12);
    float pts = 0.f;
#pragma unroll
    for (int u = 0; u < 3; ++u) {
      float4 kpv = kpb[u];
      float d;
      d = qpsm[u*4+0]-kpv.x; pts = fmaf(d,d,pts);
      d = qpsm[u*4+1]-kpv.y; pts = fmaf(d,d,pts);
      d = qpsm[u*4+2]-kpv.z; pts = fmaf(d,d,pts);
      d = qpsm[u*4+3]-kpv.w; pts = fmaf(d,d,pts);
    }
    float bterm = bmat[((size_t)i*HD + h)*NN + j];
    float lg = fmaf(dot, s1, bterm) + coef*pts + 100000.0f*(mi*mask[j] - 1.0f);
    l3[jj] = lg; ss3[jj] = ss[i*NN + j];
  }
  float mx = fmaxf(l3[0], fmaxf(l3[1], l3[2]));
#pragma unroll
  for (int off = 32; off >= 1; off >>= 1) mx = fmaxf(mx, __shfl_xor(mx, off));
  if ((t & 63) == 0) wred[t>>6] = mx;
  __syncthreads();
  mx = fmaxf(fmaxf(wred[0],wred[1]), fmaxf(wred[2],wred[3]));
  float e3[3]; float sum = 0.f;
#pragma unroll
  for (int jj = 0; jj < 3; ++jj) {
    e3[jj] = __expf(l3[jj]-mx) * (__expf(ss3[jj]) - 0.99f);
    sum += e3[jj];
  }
#pragma unroll
  for (int off = 32; off >= 1; off >>= 1) sum += __shfl_xor(sum, off);
  if ((t & 63) == 0) wred[4 + (t>>6)] = sum;
  __syncthreads();
  sum = (wred[4]+wred[5]) + (wred[6]+wred[7]);
  float inv = 1.0f / sum;
#pragma unroll
  for (int jj = 0; jj < 3; ++jj)
    abuf[((size_t)h*NN + i)*NN + t + jj*256] = e3[jj]*inv;
}

// ---------------- K4: o and o_pt (+norm) -> cat[0:576) ----------------
__global__ __launch_bounds__(256) void k_out_v(
    const float* __restrict__ rot, const float* __restrict__ trans, float* __restrict__ ws) {
  int h = blockIdx.x;
  int i = blockIdx.y*4 + (threadIdx.x >> 6);
  int lane = threadIdx.x & 63;
  const float* abuf = ws + OFF_A; const float* vbuf = ws + OFF_V; const float* vpbuf = ws + OFF_VP;
  float* cat = ws + OFF_CAT;
  const float* arow = abuf + ((size_t)h*NN + i)*NN;
  float acc = 0.f;
  if (lane < 40) {
    const float* ptr; int stride;
    if (lane < 16) { ptr = vbuf + (size_t)(h*NN)*CD + lane; stride = CD; }
    else           { ptr = vpbuf + (size_t)(h*NN)*24 + (lane-16); stride = 24; }
    for (int j = 0; j < NN; j += 4) {
      float4 a4 = *(const float4*)(arow + j);
      float x0 = ptr[0];
      float x1 = ptr[stride];
      float x2 = ptr[2*stride];
      float x3 = ptr[3*stride];
      ptr += 4*stride;
      acc = fmaf(a4.x, x0, acc);
      acc = fmaf(a4.y, x1, acc);
      acc = fmaf(a4.z, x2, acc);
      acc = fmaf(a4.w, x3, acc);
    }
  }
  if (lane < 16) {
    cat[(size_t)i*CATD + h*CD + lane] = acc;
  } else if (lane < 40) {
    int pv = lane - 16; int p = pv/3; int x = pv - 3*p;
    int base = 16 + p*3;
    float g0 = __shfl(acc, base+0);
    float g1 = __shfl(acc, base+1);
    float g2 = __shfl(acc, base+2);
    float v0 = g0 - trans[i*3+0];
    float v1 = g1 - trans[i*3+1];
    float v2 = g2 - trans[i*3+2];
    float loc = rot[i*9 + 0*3 + x]*v0 + rot[i*9 + 1*3 + x]*v1 + rot[i*9 + 2*3 + x]*v2;
    cat[(size_t)i*CATD + 192 + x*96 + h*PVD + p] = loc;
    float sq = loc*loc;
    float n2 = __shfl(sq, base+0) + __shfl(sq, base+1) + __shfl(sq, base+2);
    if (x == 0) cat[(size_t)i*CATD + 480 + h*PVD + p] = sqrtf(n2 + 1e-8f);
  }
}

// ---------------- K5: o_pair = a . z -> cat[576:2112) ----------------
__global__ __launch_bounds__(256) void k_out_pair(const float* __restrict__ z, float* __restrict__ ws) {
  __shared__ float a_sm[HD*NN];        // 36 KB
  __shared__ float4 psm[4][HD][32];    // 24 KB
  int i = blockIdx.x;
  int t = threadIdx.x;
  const float* abuf = ws + OFF_A;
  float* cat = ws + OFF_CAT;
  for (int h = 0; h < HD; ++h) {
    if (t < 192)
      *(float4*)&a_sm[h*NN + t*4] = *(const float4*)(abuf + ((size_t)h*NN + i)*NN + t*4);
  }
  __syncthreads();
  int c4 = t & 31, jc = t >> 5;
  const float* zbase = z + ((size_t)i*NN + (size_t)jc*96)*CZD + c4*4;
  float4 acc[12];
#pragma unroll
  for (int h = 0; h < 12; ++h) acc[h] = make_float4(0.f,0.f,0.f,0.f);
  float4 zn0 = *(const float4*)(zbase);
  float4 zn1 = *(const float4*)(zbase + CZD);
  for (int jj = 0; jj < 96; jj += 2) {
    float4 z0 = zn0, z1 = zn1;
    if (jj + 2 < 96) {
      zn0 = *(const float4*)(zbase + (size_t)(jj+2)*CZD);
      zn1 = *(const float4*)(zbase + (size_t)(jj+3)*CZD);
    }
    int j0 = jc*96 + jj;
#pragma unroll
    for (int h = 0; h < 12; ++h) {
      float af = a_sm[h*NN + j0];
      acc[h].x = fmaf(af, z0.x, acc[h].x);
      acc[h].y = fmaf(af, z0.y, acc[h].y);
      acc[h].z = fmaf(af, z0.z, acc[h].z);
      acc[h].w = fmaf(af, z0.w, acc[h].w);
    }
#pragma unroll
    for (int h = 0; h < 12; ++h) {
      float af = a_sm[h*NN + j0 + 1];
      acc[h].x = fmaf(af, z1.x, acc[h].x);
      acc[h].y = fmaf(af, z1.y, acc[h].y);
      acc[h].z = fmaf(af, z1.z, acc[h].z);
      acc[h].w = fmaf(af, z1.w, acc[h].w);
    }
  }
  int wv = t >> 6, ln = t & 63;
#pragma unroll
  for (int h = 0; h < 12; ++h) {
    acc[h].x += __shfl_down(acc[h].x, 32);
    acc[h].y += __shfl_down(acc[h].y, 32);
    acc[h].z += __shfl_down(acc[h].z, 32);
    acc[h].w += __shfl_down(acc[h].w, 32);
  }
  if (ln < 32) {
#pragma unroll
    for (int h = 0; h < 12; ++h) psm[wv][h][ln] = acc[h];
  }
  __syncthreads();
  for (int o = t; o < 384; o += 256) {
    int h = o >> 5, cc = o & 31;
    float4 s0 = psm[0][h][cc], s1 = psm[1][h][cc], s2 = psm[2][h][cc], s3 = psm[3][h][cc];
    float4 r;
    r.x = (s0.x+s1.x)+(s2.x+s3.x);
    r.y = (s0.y+s1.y)+(s2.y+s3.y);
    r.z = (s0.z+s1.z)+(s2.z+s3.z);
    r.w = (s0.w+s1.w)+(s2.w+s3.w);
    *(float4*)&cat[(size_t)i*CATD + 576 + h*CZD + cc*4] = r;
  }
}

// ---------------- K6: out = cat @ W_out + b_out ----------------
__global__ __launch_bounds__(256) void k_init_out(const float* __restrict__ bout, float* __restrict__ out) {
  int idx = blockIdx.x*256 + threadIdx.x;
  if (idx < NN*CSD) out[idx] = bout[idx % CSD];
}

__global__ __launch_bounds__(256) void k_final(const float* __restrict__ Wout,
    float* __restrict__ out, const float* __restrict__ ws) {
  __shared__ float At[64*17];
  __shared__ float Bt[16*64];
  const float* cat = ws + OFF_CAT;
  int t = threadIdx.x;
  int c0 = blockIdx.x*64, r0 = blockIdx.y*64;
  int kstart = blockIdx.z*528;
  float acc[4][4] = {};
  int cc = t & 15, rr = t >> 4;
  for (int kt = 0; kt < 528; kt += 16) {
    int ka = t & 15, mb = t >> 4;
#pragma unroll
    for (int p = 0; p < 4; ++p) {
      int m = mb + p*16;
      At[m*17 + ka] = cat[(size_t)(r0+m)*CATD + kstart + kt + ka];
    }
    int cb = t & 63, kb = t >> 6;
#pragma unroll
    for (int p = 0; p < 4; ++p) {
      int kk = kb + p*4;
      Bt[kk*64 + cb] = Wout[(size_t)(kstart+kt+kk)*CSD + c0 + cb];
    }
    __syncthreads();
#pragma unroll
    for (int k = 0; k < 16; ++k) {
      float a0 = At[(rr*4+0)*17 + k];
      float a1 = At[(rr*4+1)*17 + k];
      float a2 = At[(rr*4+2)*17 + k];
      float a3 = At[(rr*4+3)*17 + k];
      float4 b4 = *(const float4*)&Bt[k*64 + cc*4];
      acc[0][0] = fmaf(a0,b4.x,acc[0][0]); acc[0][1] = fmaf(a0,b4.y,acc[0][1]);
      acc[0][2] = fmaf(a0,b4.z,acc[0][2]); acc[0][3] = fmaf(a0,b4.w,acc[0][3]);
      acc[1][0] = fmaf(a1,b4.x,acc[1][0]); acc[1][1] = fmaf(a1,b4.y,acc[1][1]);
      acc[1][2] = fmaf(a1,b4.z,acc[1][2]); acc[1][3] = fmaf(a1,b4.w,acc[1][3]);
      acc[2][0] = fmaf(a2,b4.x,acc[2][0]); acc[2][1] = fmaf(a2,b4.y,acc[2][1]);
      acc[2][2] = fmaf(a2,b4.z,acc[2][2]); acc[2][3] = fmaf(a2,b4.w,acc[2][3]);
      acc[3][0] = fmaf(a3,b4.x,acc[3][0]); acc[3][1] = fmaf(a3,b4.y,acc[3][1]);
      acc[3][2] = fmaf(a3,b4.z,acc[3][2]); acc[3][3] = fmaf(a3,b4.w,acc[3][3]);
    }
    __syncthreads();
  }
#pragma unroll
  for (int ii = 0; ii < 4; ++ii)
#pragma unroll
    for (int jj = 0; jj < 4; ++jj)
      atomicAdd(&out[(size_t)(r0+rr*4+ii)*CSD + c0 + cc*4 + jj], acc[ii][jj]);
}

extern "C" void kernel_launch(void* const* d_in, const int* in_sizes, int n_in,
                              void* d_out, int out_size, void* d_ws, size_t ws_size,
                              hipStream_t stream) {
  const float* s    = (const float*)d_in[0];
  const float* z    = (const float*)d_in[1];
  const float* rot  = (const float*)d_in[2];
  const float* trans= (const float*)d_in[3];
  const float* mask = (const float*)d_in[4];
  const float* ss   = (const float*)d_in[5];
  const float* Wq   = (const float*)d_in[6];
  const float* bq   = (const float*)d_in[7];
  const float* Wkv  = (const float*)d_in[8];
  const float* bkv  = (const float*)d_in[9];
  const float* Wqp  = (const float*)d_in[10];
  const float* bqp  = (const float*)d_in[11];
  const float* Wkvp = (const float*)d_in[12];
  const float* bkvp = (const float*)d_in[13];
  const float* Wb   = (const float*)d_in[14];
  const float* bb   = (const float*)d_in[15];
  const float* hw   = (const float*)d_in[16];
  const float* Wout = (const float*)d_in[17];
  const float* bout = (const float*)d_in[18];
  float* ws  = (float*)d_ws;
  float* out = (float*)d_out;

  hipLaunchKernelGGL(k_proj, dim3(18,12), dim3(256), 0, stream,
                     s, Wq,bq, Wkv,bkv, Wqp,bqp, Wkvp,bkvp, ws);
  hipLaunchKernelGGL(k_points, dim3(576), dim3(256), 0, stream, rot, trans, ws);
  hipLaunchKernelGGL(k_bias, dim3(768,4), dim3(256), 0, stream, z, Wb, bb, ws);
  hipLaunchKernelGGL(k_attn, dim3(12,768), dim3(256), 0, stream, mask, ss, hw, ws);
  hipLaunchKernelGGL(k_out_v, dim3(12,192), dim3(256), 0, stream, rot, trans, ws);
  hipLaunchKernelGGL(k_out_pair, dim3(768), dim3(256), 0, stream, z, ws);
  hipLaunchKernelGGL(k_init_out, dim3(1152), dim3(256), 0, stream, bout, out);
  hipLaunchKernelGGL(k_final, dim3(6,12,4), dim3(256), 0, stream, Wout, out, ws);
}

// Round 3
// 906.042 us; speedup vs baseline: 1.0530x; 1.0530x over previous
//
#include <hip/hip_runtime.h>
#include <math.h>

#define NN 768
#define CSD 384
#define HD 12
#define CD 16
#define PQD 4
#define PVD 8
#define CZD 128
#define CATD 2112

// ws float offsets
#define OFF_Q      0u
#define OFF_K      147456u
#define OFF_V      294912u
#define OFF_QP     442368u
#define OFF_KP     552960u
#define OFF_VP     663552u
#define OFF_RAW    884736u
#define OFF_B      1327104u
#define OFF_A      8404992u
#define OFF_CAT    15482880u

__device__ __forceinline__ float wcol_val(const float* Wq, const float* Wkv,
                                          const float* Wqp, const float* Wkvp,
                                          int k, int col) {
  if (col < 192) return Wq[k*192 + col];
  if (col < 576) return Wkv[k*384 + (col-192)];
  if (col < 720) return Wqp[k*144 + (col-576)];
  return Wkvp[k*432 + (col-720)];
}
__device__ __forceinline__ float bias_val(const float* bq, const float* bkv,
                                          const float* bqp, const float* bkvp, int col) {
  if (col < 192) return bq[col];
  if (col < 576) return bkv[col-192];
  if (col < 720) return bqp[col-576];
  return bkvp[col-720];
}

// ---------------- K1: s @ [W_q | W_kv | W_qp | W_kvp] + bias ----------------
__global__ __launch_bounds__(256) void k_proj(const float* __restrict__ s,
    const float* __restrict__ Wq, const float* __restrict__ bq,
    const float* __restrict__ Wkv, const float* __restrict__ bkv,
    const float* __restrict__ Wqp, const float* __restrict__ bqp,
    const float* __restrict__ Wkvp, const float* __restrict__ bkvp,
    float* __restrict__ ws) {
  __shared__ float At[64*17];   // [m][k], padded
  __shared__ float Bt[16*64];   // [k][c]
  int t = threadIdx.x;
  int c0 = blockIdx.x * 64;
  int r0 = blockIdx.y * 64;
  float acc[4][4] = {};
  int cc = t & 15, rr = t >> 4;
  for (int kt = 0; kt < CSD; kt += 16) {
    int ka = t & 15, mb = t >> 4;
#pragma unroll
    for (int p = 0; p < 4; ++p) {
      int m = mb + p*16;
      At[m*17 + ka] = s[(r0+m)*CSD + kt + ka];
    }
    int cb = t & 63, kb = t >> 6;
#pragma unroll
    for (int p = 0; p < 4; ++p) {
      int kk = kb + p*4;
      Bt[kk*64 + cb] = wcol_val(Wq,Wkv,Wqp,Wkvp, kt+kk, c0+cb);
    }
    __syncthreads();
#pragma unroll
    for (int k = 0; k < 16; ++k) {
      float a0 = At[(rr*4+0)*17 + k];
      float a1 = At[(rr*4+1)*17 + k];
      float a2 = At[(rr*4+2)*17 + k];
      float a3 = At[(rr*4+3)*17 + k];
      float4 b4 = *(const float4*)&Bt[k*64 + cc*4];
      acc[0][0] = fmaf(a0,b4.x,acc[0][0]); acc[0][1] = fmaf(a0,b4.y,acc[0][1]);
      acc[0][2] = fmaf(a0,b4.z,acc[0][2]); acc[0][3] = fmaf(a0,b4.w,acc[0][3]);
      acc[1][0] = fmaf(a1,b4.x,acc[1][0]); acc[1][1] = fmaf(a1,b4.y,acc[1][1]);
      acc[1][2] = fmaf(a1,b4.z,acc[1][2]); acc[1][3] = fmaf(a1,b4.w,acc[1][3]);
      acc[2][0] = fmaf(a2,b4.x,acc[2][0]); acc[2][1] = fmaf(a2,b4.y,acc[2][1]);
      acc[2][2] = fmaf(a2,b4.z,acc[2][2]); acc[2][3] = fmaf(a2,b4.w,acc[2][3]);
      acc[3][0] = fmaf(a3,b4.x,acc[3][0]); acc[3][1] = fmaf(a3,b4.y,acc[3][1]);
      acc[3][2] = fmaf(a3,b4.z,acc[3][2]); acc[3][3] = fmaf(a3,b4.w,acc[3][3]);
    }
    __syncthreads();
  }
  float* qbuf = ws + OFF_Q; float* kbuf = ws + OFF_K; float* vbuf = ws + OFF_V;
  float* raw  = ws + OFF_RAW;
#pragma unroll
  for (int jj = 0; jj < 4; ++jj) {
    int col = c0 + cc*4 + jj;
    float bv = bias_val(bq,bkv,bqp,bkvp,col);
#pragma unroll
    for (int ii = 0; ii < 4; ++ii) {
      int row = r0 + rr*4 + ii;
      float val = acc[ii][jj] + bv;
      if (col < 192) {
        int h = col >> 4, c = col & 15;
        qbuf[(h*NN + row)*CD + c] = val;
      } else if (col < 576) {
        int u = col - 192; int h = u >> 5; int c2 = u & 31;
        if (c2 < 16) kbuf[(h*NN+row)*CD + c2] = val;
        else         vbuf[(h*NN+row)*CD + (c2-16)] = val;
      } else {
        raw[row*576 + (col-576)] = val;
      }
    }
  }
}

// ---------------- K1b: rotate+translate points ----------------
__global__ __launch_bounds__(256) void k_points(const float* __restrict__ rot,
    const float* __restrict__ trans, float* __restrict__ ws) {
  int tg = blockIdx.x*256 + threadIdx.x;      // < 768*192
  int n = tg / 192, pidx = tg % 192;
  const float* raw = ws + OFF_RAW + n*576;
  float v0, v1, v2;
  if (pidx < 48) { v0 = raw[pidx]; v1 = raw[48+pidx]; v2 = raw[96+pidx]; }
  else { int pp = pidx-48; v0 = raw[144+pp]; v1 = raw[288+pp]; v2 = raw[432+pp]; }
  const float* R = rot + n*9; const float* T = trans + n*3;
  float g0 = R[0]*v0 + R[1]*v1 + R[2]*v2 + T[0];
  float g1 = R[3]*v0 + R[4]*v1 + R[5]*v2 + T[1];
  float g2 = R[6]*v0 + R[7]*v1 + R[8]*v2 + T[2];
  if (pidx < 48) {
    int h = pidx >> 2, p = pidx & 3;
    float* qp = ws + OFF_QP + ((h*NN + n)*PQD + p)*3;
    qp[0]=g0; qp[1]=g1; qp[2]=g2;
  } else {
    int pp = pidx - 48; int h = pp/12; int q12 = pp - 12*h;
    if (q12 < 4) { float* kp = ws + OFF_KP + ((h*NN+n)*PQD + q12)*3; kp[0]=g0; kp[1]=g1; kp[2]=g2; }
    else         { float* vp = ws + OFF_VP + ((h*NN+n)*PVD + (q12-4))*3; vp[0]=g0; vp[1]=g1; vp[2]=g2; }
  }
}

// ---------------- K2 v4: bmat = sqrt(1/3)*(z @ W_b + b_b), layout (i,h,j) ----------------
// DS-minimal design: each lane owns 4 full z rows (contiguous 64B reads, full
// cache-line use via L1); Wb read as wave-uniform ds_read_b128 broadcasts
// amortized over the 4 rows (1.5 DS ops per j-row).
// grid (192, 3): block = 4 waves; wave w handles i = bx*4+w, j in [by*256, +256).
__global__ __launch_bounds__(256) void k_bias(const float* __restrict__ z,
    const float* __restrict__ Wb, const float* __restrict__ bb, float* __restrict__ ws) {
  __shared__ float wb_sm[CZD*HD];   // [c][h], rows 48B, 16B-aligned
  __shared__ float bb_sm[HD];
  int t = threadIdx.x;
  for (int idx = t; idx < CZD*HD; idx += 256) wb_sm[idx] = Wb[idx];
  if (t < HD) bb_sm[t] = bb[t];
  __syncthreads();

  int w = t >> 6, lane = t & 63;
  int i = blockIdx.x*4 + w;
  int jbase = blockIdx.y*256;
  const float* zrow = z + ((size_t)i*NN + jbase + lane)*CZD;  // row r at +r*64*CZD
  float acc[4][12];
#pragma unroll
  for (int r = 0; r < 4; ++r)
#pragma unroll
    for (int h = 0; h < 12; ++h) acc[r][h] = 0.f;

  for (int c0 = 0; c0 < CZD; c0 += 16) {
    float4 zr[4][4];
#pragma unroll
    for (int r = 0; r < 4; ++r)
#pragma unroll
      for (int u = 0; u < 4; ++u)
        zr[r][u] = *(const float4*)(zrow + (size_t)r*64*CZD + c0 + 4*u);
#pragma unroll
    for (int u = 0; u < 4; ++u) {
#pragma unroll
      for (int cc = 0; cc < 4; ++cc) {
        int c = c0 + 4*u + cc;
        float4 w0 = *(const float4*)&wb_sm[c*12];
        float4 w1 = *(const float4*)&wb_sm[c*12 + 4];
        float4 w2 = *(const float4*)&wb_sm[c*12 + 8];
#pragma unroll
        for (int r = 0; r < 4; ++r) {
          float zv = (cc==0) ? zr[r][u].x : (cc==1) ? zr[r][u].y : (cc==2) ? zr[r][u].z : zr[r][u].w;
          acc[r][0] = fmaf(zv, w0.x, acc[r][0]); acc[r][1] = fmaf(zv, w0.y, acc[r][1]);
          acc[r][2] = fmaf(zv, w0.z, acc[r][2]); acc[r][3] = fmaf(zv, w0.w, acc[r][3]);
          acc[r][4] = fmaf(zv, w1.x, acc[r][4]); acc[r][5] = fmaf(zv, w1.y, acc[r][5]);
          acc[r][6] = fmaf(zv, w1.z, acc[r][6]); acc[r][7] = fmaf(zv, w1.w, acc[r][7]);
          acc[r][8] = fmaf(zv, w2.x, acc[r][8]); acc[r][9] = fmaf(zv, w2.y, acc[r][9]);
          acc[r][10] = fmaf(zv, w2.z, acc[r][10]); acc[r][11] = fmaf(zv, w2.w, acc[r][11]);
        }
      }
    }
  }
  float* bmat = ws + OFF_B;
  const float s2 = 0.57735026918962576f;
#pragma unroll
  for (int r = 0; r < 4; ++r) {
    int j = jbase + r*64 + lane;
#pragma unroll
    for (int h = 0; h < 12; ++h)
      bmat[((size_t)i*HD + h)*NN + j] = s2*(acc[r][h] + bb_sm[h]);
  }
}

// ---------------- K3: logits + softmax -> a (h,i,j) ----------------
__global__ __launch_bounds__(256) void k_attn(
    const float* __restrict__ mask, const float* __restrict__ ss,
    const float* __restrict__ hwts, float* __restrict__ ws) {
  int h = blockIdx.x, i = blockIdx.y;
  int t = threadIdx.x;
  __shared__ float qsm[16];
  __shared__ float qpsm[12];
  __shared__ float wred[8];
  const float* qbuf = ws + OFF_Q; const float* kbuf = ws + OFF_K;
  const float* qp   = ws + OFF_QP; const float* kp  = ws + OFF_KP;
  const float* bmat = ws + OFF_B;
  float* abuf = ws + OFF_A;
  if (t < 16) qsm[t] = qbuf[(h*NN+i)*CD + t];
  else if (t < 28) qpsm[t-16] = qp[(h*NN+i)*12 + (t-16)];
  __syncthreads();
  float coef = -0.5f * 0.13608276348795434f * log1pf(__expf(hwts[h]));
  float mi = mask[i];
  const float s1 = 0.14433756729740643f;
  float l3[3], ss3[3];
#pragma unroll
  for (int jj = 0; jj < 3; ++jj) {
    int j = t + jj*256;
    const float4* kb = (const float4*)(kbuf + (h*NN+j)*CD);
    float dot = 0.f;
#pragma unroll
    for (int u = 0; u < 4; ++u) {
      float4 kv = kb[u];
      dot = fmaf(qsm[u*4+0], kv.x, dot);
      dot = fmaf(qsm[u*4+1], kv.y, dot);
      dot = fmaf(qsm[u*4+2], kv.z, dot);
      dot = fmaf(qsm[u*4+3], kv.w, dot);
    }
    const float4* kpb = (const float4*)(kp + (h*NN+j)*12);
    float pts = 0.f;
#pragma unroll
    for (int u = 0; u < 3; ++u) {
      float4 kpv = kpb[u];
      float d;
      d = qpsm[u*4+0]-kpv.x; pts = fmaf(d,d,pts);
      d = qpsm[u*4+1]-kpv.y; pts = fmaf(d,d,pts);
      d = qpsm[u*4+2]-kpv.z; pts = fmaf(d,d,pts);
      d = qpsm[u*4+3]-kpv.w; pts = fmaf(d,d,pts);
    }
    float bterm = bmat[((size_t)i*HD + h)*NN + j];
    float lg = fmaf(dot, s1, bterm) + coef*pts + 100000.0f*(mi*mask[j] - 1.0f);
    l3[jj] = lg; ss3[jj] = ss[i*NN + j];
  }
  float mx = fmaxf(l3[0], fmaxf(l3[1], l3[2]));
#pragma unroll
  for (int off = 32; off >= 1; off >>= 1) mx = fmaxf(mx, __shfl_xor(mx, off));
  if ((t & 63) == 0) wred[t>>6] = mx;
  __syncthreads();
  mx = fmaxf(fmaxf(wred[0],wred[1]), fmaxf(wred[2],wred[3]));
  float e3[3]; float sum = 0.f;
#pragma unroll
  for (int jj = 0; jj < 3; ++jj) {
    e3[jj] = __expf(l3[jj]-mx) * (__expf(ss3[jj]) - 0.99f);
    sum += e3[jj];
  }
#pragma unroll
  for (int off = 32; off >= 1; off >>= 1) sum += __shfl_xor(sum, off);
  if ((t & 63) == 0) wred[4 + (t>>6)] = sum;
  __syncthreads();
  sum = (wred[4]+wred[5]) + (wred[6]+wred[7]);
  float inv = 1.0f / sum;
#pragma unroll
  for (int jj = 0; jj < 3; ++jj)
    abuf[((size_t)h*NN + i)*NN + t + jj*256] = e3[jj]*inv;
}

// ---------------- K4: o and o_pt (+norm) -> cat[0:576) ----------------
__global__ __launch_bounds__(256) void k_out_v(
    const float* __restrict__ rot, const float* __restrict__ trans, float* __restrict__ ws) {
  int h = blockIdx.x;
  int i = blockIdx.y*4 + (threadIdx.x >> 6);
  int lane = threadIdx.x & 63;
  const float* abuf = ws + OFF_A; const float* vbuf = ws + OFF_V; const float* vpbuf = ws + OFF_VP;
  float* cat = ws + OFF_CAT;
  const float* arow = abuf + ((size_t)h*NN + i)*NN;
  float acc = 0.f;
  if (lane < 40) {
    const float* ptr; int stride;
    if (lane < 16) { ptr = vbuf + (size_t)(h*NN)*CD + lane; stride = CD; }
    else           { ptr = vpbuf + (size_t)(h*NN)*24 + (lane-16); stride = 24; }
    for (int j = 0; j < NN; j += 4) {
      float4 a4 = *(const float4*)(arow + j);
      float x0 = ptr[0];
      float x1 = ptr[stride];
      float x2 = ptr[2*stride];
      float x3 = ptr[3*stride];
      ptr += 4*stride;
      acc = fmaf(a4.x, x0, acc);
      acc = fmaf(a4.y, x1, acc);
      acc = fmaf(a4.z, x2, acc);
      acc = fmaf(a4.w, x3, acc);
    }
  }
  if (lane < 16) {
    cat[(size_t)i*CATD + h*CD + lane] = acc;
  } else if (lane < 40) {
    int pv = lane - 16; int p = pv/3; int x = pv - 3*p;
    int base = 16 + p*3;
    float g0 = __shfl(acc, base+0);
    float g1 = __shfl(acc, base+1);
    float g2 = __shfl(acc, base+2);
    float v0 = g0 - trans[i*3+0];
    float v1 = g1 - trans[i*3+1];
    float v2 = g2 - trans[i*3+2];
    float loc = rot[i*9 + 0*3 + x]*v0 + rot[i*9 + 1*3 + x]*v1 + rot[i*9 + 2*3 + x]*v2;
    cat[(size_t)i*CATD + 192 + x*96 + h*PVD + p] = loc;
    float sq = loc*loc;
    float n2 = __shfl(sq, base+0) + __shfl(sq, base+1) + __shfl(sq, base+2);
    if (x == 0) cat[(size_t)i*CATD + 480 + h*PVD + p] = sqrtf(n2 + 1e-8f);
  }
}

// ---------------- K5 v2: o_pair = a . z -> cat[576:2112) ----------------
// a_sm reads now float4 (b128 broadcast, <=2 distinct addrs/wave) amortized
// over 4 j per step: 288 DS ops/wave/block vs ~1200 before.
__global__ __launch_bounds__(256) void k_out_pair(const float* __restrict__ z, float* __restrict__ ws) {
  __shared__ float a_sm[HD*NN];        // 36 KB
  __shared__ float4 psm[4][HD][32];    // 24 KB
  int i = blockIdx.x;
  int t = threadIdx.x;
  const float* abuf = ws + OFF_A;
  float* cat = ws + OFF_CAT;
  for (int h = 0; h < HD; ++h) {
    if (t < 192)
      *(float4*)&a_sm[h*NN + t*4] = *(const float4*)(abuf + ((size_t)h*NN + i)*NN + t*4);
  }
  __syncthreads();
  int c4 = t & 31, jc = t >> 5;     // 8 j-slices of 96; wave holds 2 slices
  const float* zbase = z + ((size_t)i*NN + (size_t)jc*96)*CZD + c4*4;
  float4 acc[12];
#pragma unroll
  for (int h = 0; h < 12; ++h) acc[h] = make_float4(0.f,0.f,0.f,0.f);
  for (int jj = 0; jj < 96; jj += 4) {
    float4 z0 = *(const float4*)(zbase + (size_t)(jj+0)*CZD);
    float4 z1 = *(const float4*)(zbase + (size_t)(jj+1)*CZD);
    float4 z2 = *(const float4*)(zbase + (size_t)(jj+2)*CZD);
    float4 z3 = *(const float4*)(zbase + (size_t)(jj+3)*CZD);
    int j0 = jc*96 + jj;
#pragma unroll
    for (int h = 0; h < 12; ++h) {
      float4 av = *(const float4*)&a_sm[h*NN + j0];
      acc[h].x = fmaf(av.x, z0.x, acc[h].x); acc[h].y = fmaf(av.x, z0.y, acc[h].y);
      acc[h].z = fmaf(av.x, z0.z, acc[h].z); acc[h].w = fmaf(av.x, z0.w, acc[h].w);
      acc[h].x = fmaf(av.y, z1.x, acc[h].x); acc[h].y = fmaf(av.y, z1.y, acc[h].y);
      acc[h].z = fmaf(av.y, z1.z, acc[h].z); acc[h].w = fmaf(av.y, z1.w, acc[h].w);
      acc[h].x = fmaf(av.z, z2.x, acc[h].x); acc[h].y = fmaf(av.z, z2.y, acc[h].y);
      acc[h].z = fmaf(av.z, z2.z, acc[h].z); acc[h].w = fmaf(av.z, z2.w, acc[h].w);
      acc[h].x = fmaf(av.w, z3.x, acc[h].x); acc[h].y = fmaf(av.w, z3.y, acc[h].y);
      acc[h].z = fmaf(av.w, z3.z, acc[h].z); acc[h].w = fmaf(av.w, z3.w, acc[h].w);
    }
  }
  int wv = t >> 6, ln = t & 63;
#pragma unroll
  for (int h = 0; h < 12; ++h) {
    acc[h].x += __shfl_down(acc[h].x, 32);
    acc[h].y += __shfl_down(acc[h].y, 32);
    acc[h].z += __shfl_down(acc[h].z, 32);
    acc[h].w += __shfl_down(acc[h].w, 32);
  }
  if (ln < 32) {
#pragma unroll
    for (int h = 0; h < 12; ++h) psm[wv][h][ln] = acc[h];
  }
  __syncthreads();
  for (int o = t; o < 384; o += 256) {
    int h = o >> 5, cc = o & 31;
    float4 s0 = psm[0][h][cc], s1 = psm[1][h][cc], s2 = psm[2][h][cc], s3 = psm[3][h][cc];
    float4 r;
    r.x = (s0.x+s1.x)+(s2.x+s3.x);
    r.y = (s0.y+s1.y)+(s2.y+s3.y);
    r.z = (s0.z+s1.z)+(s2.z+s3.z);
    r.w = (s0.w+s1.w)+(s2.w+s3.w);
    *(float4*)&cat[(size_t)i*CATD + 576 + h*CZD + cc*4] = r;
  }
}

// ---------------- K6: out = cat @ W_out + b_out ----------------
__global__ __launch_bounds__(256) void k_init_out(const float* __restrict__ bout, float* __restrict__ out) {
  int idx = blockIdx.x*256 + threadIdx.x;
  if (idx < NN*CSD) out[idx] = bout[idx % CSD];
}

__global__ __launch_bounds__(256) void k_final(const float* __restrict__ Wout,
    float* __restrict__ out, const float* __restrict__ ws) {
  __shared__ float At[64*17];
  __shared__ float Bt[16*64];
  const float* cat = ws + OFF_CAT;
  int t = threadIdx.x;
  int c0 = blockIdx.x*64, r0 = blockIdx.y*64;
  int kstart = blockIdx.z*528;
  float acc[4][4] = {};
  int cc = t & 15, rr = t >> 4;
  for (int kt = 0; kt < 528; kt += 16) {
    int ka = t & 15, mb = t >> 4;
#pragma unroll
    for (int p = 0; p < 4; ++p) {
      int m = mb + p*16;
      At[m*17 + ka] = cat[(size_t)(r0+m)*CATD + kstart + kt + ka];
    }
    int cb = t & 63, kb = t >> 6;
#pragma unroll
    for (int p = 0; p < 4; ++p) {
      int kk = kb + p*4;
      Bt[kk*64 + cb] = Wout[(size_t)(kstart+kt+kk)*CSD + c0 + cb];
    }
    __syncthreads();
#pragma unroll
    for (int k = 0; k < 16; ++k) {
      float a0 = At[(rr*4+0)*17 + k];
      float a1 = At[(rr*4+1)*17 + k];
      float a2 = At[(rr*4+2)*17 + k];
      float a3 = At[(rr*4+3)*17 + k];
      float4 b4 = *(const float4*)&Bt[k*64 + cc*4];
      acc[0][0] = fmaf(a0,b4.x,acc[0][0]); acc[0][1] = fmaf(a0,b4.y,acc[0][1]);
      acc[0][2] = fmaf(a0,b4.z,acc[0][2]); acc[0][3] = fmaf(a0,b4.w,acc[0][3]);
      acc[1][0] = fmaf(a1,b4.x,acc[1][0]); acc[1][1] = fmaf(a1,b4.y,acc[1][1]);
      acc[1][2] = fmaf(a1,b4.z,acc[1][2]); acc[1][3] = fmaf(a1,b4.w,acc[1][3]);
      acc[2][0] = fmaf(a2,b4.x,acc[2][0]); acc[2][1] = fmaf(a2,b4.y,acc[2][1]);
      acc[2][2] = fmaf(a2,b4.z,acc[2][2]); acc[2][3] = fmaf(a2,b4.w,acc[2][3]);
      acc[3][0] = fmaf(a3,b4.x,acc[3][0]); acc[3][1] = fmaf(a3,b4.y,acc[3][1]);
      acc[3][2] = fmaf(a3,b4.z,acc[3][2]); acc[3][3] = fmaf(a3,b4.w,acc[3][3]);
    }
    __syncthreads();
  }
#pragma unroll
  for (int ii = 0; ii < 4; ++ii)
#pragma unroll
    for (int jj = 0; jj < 4; ++jj)
      atomicAdd(&out[(size_t)(r0+rr*4+ii)*CSD + c0 + cc*4 + jj], acc[ii][jj]);
}

extern "C" void kernel_launch(void* const* d_in, const int* in_sizes, int n_in,
                              void* d_out, int out_size, void* d_ws, size_t ws_size,
                              hipStream_t stream) {
  const float* s    = (const float*)d_in[0];
  const float* z    = (const float*)d_in[1];
  const float* rot  = (const float*)d_in[2];
  const float* trans= (const float*)d_in[3];
  const float* mask = (const float*)d_in[4];
  const float* ss   = (const float*)d_in[5];
  const float* Wq   = (const float*)d_in[6];
  const float* bq   = (const float*)d_in[7];
  const float* Wkv  = (const float*)d_in[8];
  const float* bkv  = (const float*)d_in[9];
  const float* Wqp  = (const float*)d_in[10];
  const float* bqp  = (const float*)d_in[11];
  const float* Wkvp = (const float*)d_in[12];
  const float* bkvp = (const float*)d_in[13];
  const float* Wb   = (const float*)d_in[14];
  const float* bb   = (const float*)d_in[15];
  const float* hw   = (const float*)d_in[16];
  const float* Wout = (const float*)d_in[17];
  const float* bout = (const float*)d_in[18];
  float* ws  = (float*)d_ws;
  float* out = (float*)d_out;

  hipLaunchKernelGGL(k_proj, dim3(18,12), dim3(256), 0, stream,
                     s, Wq,bq, Wkv,bkv, Wqp,bqp, Wkvp,bkvp, ws);
  hipLaunchKernelGGL(k_points, dim3(576), dim3(256), 0, stream, rot, trans, ws);
  hipLaunchKernelGGL(k_bias, dim3(192,3), dim3(256), 0, stream, z, Wb, bb, ws);
  hipLaunchKernelGGL(k_attn, dim3(12,768), dim3(256), 0, stream, mask, ss, hw, ws);
  hipLaunchKernelGGL(k_out_v, dim3(12,192), dim3(256), 0, stream, rot, trans, ws);
  hipLaunchKernelGGL(k_out_pair, dim3(768), dim3(256), 0, stream, z, ws);
  hipLaunchKernelGGL(k_init_out, dim3(1152), dim3(256), 0, stream, bout, out);
  hipLaunchKernelGGL(k_final, dim3(6,12,4), dim3(256), 0, stream, Wout, out, ws);
}